// Round 5
// baseline (385.795 us; speedup 1.0000x reference)
//
#include <hip/hip_runtime.h>
#include <hip/hip_bf16.h>

typedef short bf16x8 __attribute__((ext_vector_type(8)));
typedef float f32x4 __attribute__((ext_vector_type(4)));
typedef float f32x16 __attribute__((ext_vector_type(16)));
typedef __hip_bfloat16 bf16;
typedef unsigned int uint;

static constexpr int Bn = 4, Nn = 2048, Cn = 1024, Hn = 16, Dn = 64;
static constexpr float kEps = 1e-6f;

// async global->LDS 16B per lane (wave-uniform dest base + lane*16)
#define GLOAD_LDS16(gp, lp)                                                        \
  __builtin_amdgcn_global_load_lds(                                                \
      (const __attribute__((address_space(1))) unsigned int*)(gp),                 \
      (__attribute__((address_space(3))) unsigned int*)(lp), 16, 0, 0)

__device__ __forceinline__ float exp2_raw(float x) {  // v_exp_f32: D = 2^S0
  float r;
  asm("v_exp_f32 %0, %1" : "=v"(r) : "v"(x));
  return r;
}

// ---------------- f32 -> bf16 convert (4 elems/thread) ----------------
__global__ __launch_bounds__(256) void cvt_kernel(const float* __restrict__ in,
                                                  bf16* __restrict__ out, int n4) {
  int i = blockIdx.x * 256 + threadIdx.x;
  if (i >= n4) return;
  const float4 v = reinterpret_cast<const float4*>(in)[i];
  bf16 t[4];
  t[0] = __float2bfloat16(v.x); t[1] = __float2bfloat16(v.y);
  t[2] = __float2bfloat16(v.z); t[3] = __float2bfloat16(v.w);
  reinterpret_cast<uint2*>(out)[i] = *reinterpret_cast<const uint2*>(t);
}

// ---------------- bf16 GEMM (m97 structure), C = A(MxK) * B(NxK)^T ----------
// 128x128 tile, BK=64, linear LDS [128][64], A+B staged via global_load_lds
// width=16 (8 DMA issues per K-step), 2 barriers/K-step, 4 waves x 4x4 frags.
template <int EPI>
__global__ __launch_bounds__(256) void gemm_bt(
    const bf16* __restrict__ A, const bf16* __restrict__ Bw,
    float* __restrict__ Cf, bf16* __restrict__ q_raw, bf16* __restrict__ k_raw,
    bf16* __restrict__ v_buf, int N, int K) {
  __shared__ __align__(16) bf16 As[128 * 64];
  __shared__ __align__(16) bf16 Bs[128 * 64];
  const int tid = threadIdx.x;
  const int lane = tid & 63, w = tid >> 6;
  const int wr = w >> 1, wc = w & 1;
  const int l15 = lane & 15, l4 = lane >> 4;
  const int m0 = blockIdx.y * 128, n0 = blockIdx.x * 128;
  f32x4 acc[4][4] = {};

  // staging: thread covers rows sr + {0,32,64,96}, cols sc..sc+7
  const int sr = tid >> 3, sc = (tid & 7) * 8;
  const bf16* const Ap = A + (size_t)(m0 + sr) * K + sc;
  const bf16* const Bp = Bw + (size_t)(n0 + sr) * K + sc;
  char* const asd = (char*)As + tid * 16;
  char* const bsd = (char*)Bs + tid * 16;

  for (int k0 = 0; k0 < K; k0 += 64) {
    __syncthreads();  // prior compute's LDS reads done
#pragma unroll
    for (int c = 0; c < 4; ++c) {
      GLOAD_LDS16(Ap + (size_t)(c * 32) * K + k0, asd + c * 4096);
      GLOAD_LDS16(Bp + (size_t)(c * 32) * K + k0, bsd + c * 4096);
    }
    __syncthreads();  // vmcnt(0) drain -> staged tile visible
#pragma unroll
    for (int kc = 0; kc < 2; ++kc) {
      bf16x8 af[4], bfr[4];
#pragma unroll
      for (int mi = 0; mi < 4; ++mi)
        af[mi] = *reinterpret_cast<const bf16x8*>(
            (const char*)As + (wr * 64 + mi * 16 + l15) * 128 + kc * 64 + l4 * 16);
#pragma unroll
      for (int ni = 0; ni < 4; ++ni)
        bfr[ni] = *reinterpret_cast<const bf16x8*>(
            (const char*)Bs + (wc * 64 + ni * 16 + l15) * 128 + kc * 64 + l4 * 16);
#pragma unroll
      for (int mi = 0; mi < 4; ++mi)
#pragma unroll
        for (int ni = 0; ni < 4; ++ni)
          acc[mi][ni] =
              __builtin_amdgcn_mfma_f32_16x16x32_bf16(af[mi], bfr[ni], acc[mi][ni], 0, 0, 0);
    }
  }

#pragma unroll
  for (int mi = 0; mi < 4; ++mi)
#pragma unroll
    for (int ni = 0; ni < 4; ++ni)
#pragma unroll
      for (int r = 0; r < 4; ++r) {
        const int row = m0 + wr * 64 + mi * 16 + l4 * 4 + r;
        const int col = n0 + wc * 64 + ni * 16 + l15;
        const float v = acc[mi][ni][r];
        if (EPI == 0) {
          const int which = col >> 10, hh = (col >> 6) & 15, d = col & 63;
          const int b = row >> 11, n = row & (Nn - 1);
          const size_t idx = (((size_t)b * Hn + hh) * Nn + n) * Dn + d;
          const bf16 val = __float2bfloat16(v);
          if (which == 0) q_raw[idx] = val;
          else if (which == 1) k_raw[idx] = val;
          else v_buf[idx] = val;
        } else {
          Cf[(size_t)row * N + col] = v;
        }
      }
}

// ---------------- RMSNorm + RoPE on q,k (in place), wave per row ----------------
// q pre-scaled by D^-0.5 * log2(e) so flash_attn's softmax runs natively in
// the exp2 domain (v_exp_f32 == 2^x) with no per-score multiply.
__global__ __launch_bounds__(256) void norm_rope(bf16* __restrict__ q_raw,
                                                 bf16* __restrict__ k_raw,
                                                 const float* __restrict__ cosb,
                                                 const float* __restrict__ sinb,
                                                 const float* __restrict__ wq,
                                                 const float* __restrict__ wk) {
  const int row = blockIdx.x * 4 + (threadIdx.x >> 6);  // (b*H+h)*N + n
  const int lane = threadIdx.x & 63;
  const int n = row & (Nn - 1);
  const size_t base = (size_t)row * Dn + lane;
  const float c = cosb[n * Dn + lane], s = sinb[n * Dn + lane];
  float q = __bfloat162float(q_raw[base]);
  float k = __bfloat162float(k_raw[base]);
  float sq = q * q, sk = k * k;
#pragma unroll
  for (int off = 32; off >= 1; off >>= 1) {
    sq += __shfl_xor(sq, off);
    sk += __shfl_xor(sk, off);
  }
  const float rq = rsqrtf(sq * (1.f / Dn) + kEps) * wq[lane];
  const float rk = rsqrtf(sk * (1.f / Dn) + kEps) * wk[lane];
  const float qn = q * rq, kn = k * rk;
  const float qp = __shfl_xor(qn, 32), kp = __shfl_xor(kn, 32);
  const float sgn = (lane < 32) ? -1.f : 1.f;
  const float kQScale = 0.125f * 1.44269504088896340f;  // D^-0.5 * log2(e)
  q_raw[base] = __float2bfloat16((qn * c + sgn * qp * s) * kQScale);
  k_raw[base] = __float2bfloat16(kn * c + sgn * kp * s);
}

// ---------------- flash attention v5 ----------------
// v4 + exp2-domain softmax (raw v_exp_f32, no mul prelude) +
// launch_bounds(256,4) for 4 blocks/CU co-residency (VGPR 76 << 128 cap).
__global__ __launch_bounds__(256, 4) void flash_attn(
    const bf16* __restrict__ Qb, const bf16* __restrict__ Kb,
    const bf16* __restrict__ Vb, bf16* __restrict__ Ob) {
  __shared__ __align__(16) char KsB[2][64 * 128];  // K[k][d], swz ((k&7)<<4)
  __shared__ __align__(16) char VtB[2][64 * 128];  // V^T[d][k], swz ((((d>>3)^d)&7)<<4)
  const int bh = blockIdx.y;
  const int q0 = blockIdx.x * 128;
  const int tid = threadIdx.x, lane = tid & 63, w = tid >> 6;
  const int l31 = lane & 31, hi = lane >> 5;
  const bf16* Qp = Qb + (size_t)bh * Nn * Dn;
  const bf16* Kp = Kb + (size_t)bh * Nn * Dn;
  const bf16* Vp = Vb + (size_t)bh * Nn * Dn;

  const int qrow = q0 + w * 32 + l31;
  bf16x8 qf[4];
#pragma unroll
  for (int dm = 0; dm < 4; ++dm)
    qf[dm] = *reinterpret_cast<const bf16x8*>(&Qp[(size_t)qrow * Dn + dm * 16 + hi * 8]);

  f32x16 Ot0 = {}, Ot1 = {};
  float m_r = -1e30f, l_r = 0.f;  // m_r in exp2 units

  const int skk = tid >> 3, sd0 = (tid & 7) * 8;
  const int swzK = (skk & 7) << 4;
  const int srcKe = (((sd0 * 2) ^ swzK) >> 1);  // pre-swizzled source col (elems)

  auto stage_v = [&](char* Vn, const uint4& a, const uint4& b) {
    const uint wa[4] = {a.x, a.y, a.z, a.w}, wb[4] = {b.x, b.y, b.z, b.w};
#pragma unroll
    for (int j = 0; j < 8; ++j) {
      const int d = sd0 + j;
      const int swz = (((d >> 3) ^ d) & 7) << 4;
      const unsigned short va = (j & 1) ? (unsigned short)(wa[j >> 1] >> 16)
                                        : (unsigned short)(wa[j >> 1] & 0xffff);
      const unsigned short vb2 = (j & 1) ? (unsigned short)(wb[j >> 1] >> 16)
                                         : (unsigned short)(wb[j >> 1] & 0xffff);
      *reinterpret_cast<unsigned short*>(Vn + d * 128 + ((skk * 2) ^ swz)) = va;
      *reinterpret_cast<unsigned short*>(Vn + d * 128 + ((skk * 2 + 64) ^ swz)) = vb2;
    }
  };

  GLOAD_LDS16(Kp + (size_t)skk * Dn + srcKe, KsB[0] + tid * 16);
  GLOAD_LDS16(Kp + (size_t)(skk + 32) * Dn + srcKe, KsB[0] + tid * 16 + 4096);
  {
    uint4 cva = *reinterpret_cast<const uint4*>(&Vp[(size_t)skk * Dn + sd0]);
    uint4 cvb = *reinterpret_cast<const uint4*>(&Vp[(size_t)(skk + 32) * Dn + sd0]);
    stage_v(VtB[0], cva, cvb);
  }
  uint4 nva = *reinterpret_cast<const uint4*>(&Vp[(size_t)(64 + skk) * Dn + sd0]);
  uint4 nvb = *reinterpret_cast<const uint4*>(&Vp[(size_t)(96 + skk) * Dn + sd0]);
  __syncthreads();

  const int swzk_rd = (l31 & 7) << 4;
  int cur = 0;
  for (int k0 = 0; k0 < Nn; k0 += 64) {
    const char* Kc = KsB[cur];
    const char* Vc = VtB[cur];

    if (k0 + 64 < Nn) {
      GLOAD_LDS16(Kp + (size_t)(k0 + 64 + skk) * Dn + srcKe, KsB[cur ^ 1] + tid * 16);
      GLOAD_LDS16(Kp + (size_t)(k0 + 96 + skk) * Dn + srcKe, KsB[cur ^ 1] + tid * 16 + 4096);
      stage_v(VtB[cur ^ 1], nva, nvb);
      if (k0 + 128 < Nn) {
        nva = *reinterpret_cast<const uint4*>(&Vp[(size_t)(k0 + 128 + skk) * Dn + sd0]);
        nvb = *reinterpret_cast<const uint4*>(&Vp[(size_t)(k0 + 160 + skk) * Dn + sd0]);
      }
    }

    // ---- S^T = K · Q^T : 8 MFMAs ----
    f32x16 S0 = {}, S1 = {};
    __builtin_amdgcn_s_setprio(1);
#pragma unroll
    for (int dm = 0; dm < 4; ++dm) {
      bf16x8 kf = *reinterpret_cast<const bf16x8*>(
          Kc + l31 * 128 + ((dm * 32 + hi * 16) ^ swzk_rd));
      S0 = __builtin_amdgcn_mfma_f32_32x32x16_bf16(kf, qf[dm], S0, 0, 0, 0);
    }
#pragma unroll
    for (int dm = 0; dm < 4; ++dm) {
      bf16x8 kf = *reinterpret_cast<const bf16x8*>(
          Kc + (32 + l31) * 128 + ((dm * 32 + hi * 16) ^ swzk_rd));
      S1 = __builtin_amdgcn_mfma_f32_32x32x16_bf16(kf, qf[dm], S1, 0, 0, 0);
    }
    __builtin_amdgcn_s_setprio(0);

    // ---- online softmax in exp2 domain, lane-local (q = l31) ----
    f32x16 tm;
#pragma unroll
    for (int i = 0; i < 16; ++i) tm[i] = fmaxf(S0[i], S1[i]);
#pragma unroll
    for (int i = 0; i < 8; ++i) tm[i] = fmaxf(tm[i], tm[i + 8]);
#pragma unroll
    for (int i = 0; i < 4; ++i) tm[i] = fmaxf(tm[i], tm[i + 4]);
    float mx = fmaxf(fmaxf(tm[0], tm[1]), fmaxf(tm[2], tm[3]));
    const float full = fmaxf(mx, __shfl_xor(mx, 32));
    if (__any(full > m_r + 8.f)) {  // defer-max (T13); P bounded by 2^8
      const float mnew = fmaxf(m_r, full);
      const float al = exp2_raw(m_r - mnew);
#pragma unroll
      for (int i = 0; i < 16; ++i) { Ot0[i] *= al; Ot1[i] *= al; }
      l_r *= al;
      m_r = mnew;
    }
#pragma unroll
    for (int i = 0; i < 16; ++i) S0[i] = exp2_raw(S0[i] - m_r);
#pragma unroll
    for (int i = 0; i < 16; ++i) S1[i] = exp2_raw(S1[i] - m_r);
    float ps = 0.f;
    uint wv[2][8];
#pragma unroll
    for (int kc = 0; kc < 2; ++kc) {
      const f32x16& P = kc ? S1 : S0;
#pragma unroll
      for (int c = 0; c < 2; ++c) {
        ps += ((P[8 * c + 0] + P[8 * c + 1]) + (P[8 * c + 2] + P[8 * c + 3])) +
              ((P[8 * c + 4] + P[8 * c + 5]) + (P[8 * c + 6] + P[8 * c + 7]));
        uint w0, w1, w2, w3;
        asm("v_cvt_pk_bf16_f32 %0, %1, %2" : "=v"(w0) : "v"(P[8 * c + 0]), "v"(P[8 * c + 1]));
        asm("v_cvt_pk_bf16_f32 %0, %1, %2" : "=v"(w1) : "v"(P[8 * c + 2]), "v"(P[8 * c + 3]));
        asm("v_cvt_pk_bf16_f32 %0, %1, %2" : "=v"(w2) : "v"(P[8 * c + 4]), "v"(P[8 * c + 5]));
        asm("v_cvt_pk_bf16_f32 %0, %1, %2" : "=v"(w3) : "v"(P[8 * c + 6]), "v"(P[8 * c + 7]));
        asm("v_permlane32_swap_b32 %0, %1" : "+v"(w0), "+v"(w2));
        asm("v_permlane32_swap_b32 %0, %1" : "+v"(w1), "+v"(w3));
        wv[kc][c * 4 + 0] = w0; wv[kc][c * 4 + 1] = w1;
        wv[kc][c * 4 + 2] = w2; wv[kc][c * 4 + 3] = w3;
      }
    }
    ps += __shfl_xor(ps, 32);
    l_r += ps;

    // ---- O^T += V^T · P^T : 8 MFMAs ----
    __builtin_amdgcn_s_setprio(1);
#pragma unroll
    for (int s = 0; s < 4; ++s) {
      const uint4 uu = {wv[s >> 1][(s & 1) * 4 + 0], wv[s >> 1][(s & 1) * 4 + 1],
                        wv[s >> 1][(s & 1) * 4 + 2], wv[s >> 1][(s & 1) * 4 + 3]};
      const bf16x8 pa = __builtin_bit_cast(bf16x8, uu);
      {
        const int d = l31;
        const int swz = (((d >> 3) ^ d) & 7) << 4;
        bf16x8 vf = *reinterpret_cast<const bf16x8*>(Vc + d * 128 + ((s * 32 + hi * 16) ^ swz));
        Ot0 = __builtin_amdgcn_mfma_f32_32x32x16_bf16(vf, pa, Ot0, 0, 0, 0);
      }
      {
        const int d = 32 + l31;
        const int swz = (((d >> 3) ^ d) & 7) << 4;
        bf16x8 vf = *reinterpret_cast<const bf16x8*>(Vc + d * 128 + ((s * 32 + hi * 16) ^ swz));
        Ot1 = __builtin_amdgcn_mfma_f32_32x32x16_bf16(vf, pa, Ot1, 0, 0, 0);
      }
    }
    __builtin_amdgcn_s_setprio(0);

    __syncthreads();
    cur ^= 1;
  }

  // ---- epilogue ----
  const float inv = 1.f / l_r;
  const int b = bh >> 4, h = bh & 15;
#pragma unroll
  for (int dc = 0; dc < 2; ++dc)
#pragma unroll
    for (int a2 = 0; a2 < 4; ++a2) {
      const f32x16& O = dc ? Ot1 : Ot0;
      unsigned short u0 = __bfloat16_as_ushort(__float2bfloat16(O[a2 * 4 + 0] * inv));
      unsigned short u1 = __bfloat16_as_ushort(__float2bfloat16(O[a2 * 4 + 1] * inv));
      unsigned short u2 = __bfloat16_as_ushort(__float2bfloat16(O[a2 * 4 + 2] * inv));
      unsigned short u3 = __bfloat16_as_ushort(__float2bfloat16(O[a2 * 4 + 3] * inv));
      uint2 pk;
      pk.x = (uint)u0 | ((uint)u1 << 16);
      pk.y = (uint)u2 | ((uint)u3 << 16);
      const int col = h * 64 + dc * 32 + a2 * 8 + hi * 4;
      *reinterpret_cast<uint2*>(&Ob[((size_t)(b * Nn + qrow)) * Cn + col]) = pk;
    }
}

extern "C" void kernel_launch(void* const* d_in, const int* in_sizes, int n_in,
                              void* d_out, int out_size, void* d_ws, size_t ws_size,
                              hipStream_t stream) {
  const float* hs   = (const float*)d_in[0];
  const float* cosb = (const float*)d_in[1];
  const float* sinb = (const float*)d_in[2];
  const float* qkvw = (const float*)d_in[3];
  const float* outw = (const float*)d_in[4];
  const float* nqw  = (const float*)d_in[5];
  const float* nkw  = (const float*)d_in[6];
  float* out = (float*)d_out;

  char* ws = (char*)d_ws;
  size_t off = 0;
  bf16* hs_b   = (bf16*)(ws + off); off += (size_t)Bn * Nn * Cn * 2;
  bf16* qkvw_b = (bf16*)(ws + off); off += (size_t)3 * Cn * Cn * 2;
  bf16* outw_b = (bf16*)(ws + off); off += (size_t)Cn * Cn * 2;
  bf16* q_raw  = (bf16*)(ws + off); off += (size_t)Bn * Hn * Nn * Dn * 2;
  bf16* k_raw  = (bf16*)(ws + off); off += (size_t)Bn * Hn * Nn * Dn * 2;
  bf16* v_buf  = (bf16*)(ws + off); off += (size_t)Bn * Hn * Nn * Dn * 2;
  bf16* attn   = (bf16*)(ws + off); off += (size_t)Bn * Nn * Cn * 2;

  cvt_kernel<<<(Bn * Nn * Cn / 4 + 255) / 256, 256, 0, stream>>>(hs, hs_b, Bn * Nn * Cn / 4);
  cvt_kernel<<<(3 * Cn * Cn / 4 + 255) / 256, 256, 0, stream>>>(qkvw, qkvw_b, 3 * Cn * Cn / 4);
  cvt_kernel<<<(Cn * Cn / 4 + 255) / 256, 256, 0, stream>>>(outw, outw_b, Cn * Cn / 4);

  gemm_bt<0><<<dim3(3 * Cn / 128, Bn * Nn / 128), 256, 0, stream>>>(
      hs_b, qkvw_b, nullptr, q_raw, k_raw, v_buf, 3 * Cn, Cn);

  norm_rope<<<(Bn * Hn * Nn) / 4, 256, 0, stream>>>(q_raw, k_raw, cosb, sinb, nqw, nkw);

  flash_attn<<<dim3(Nn / 128, Bn * Hn), 256, 0, stream>>>(q_raw, k_raw, v_buf, attn);

  gemm_bt<1><<<dim3(Cn / 128, Bn * Nn / 128), 256, 0, stream>>>(
      attn, outw_b, out, nullptr, nullptr, nullptr, Cn, Cn);
}

// Round 6
// 257.826 us; speedup vs baseline: 1.4963x; 1.4963x over previous
//
#include <hip/hip_runtime.h>
#include <hip/hip_bf16.h>

typedef short bf16x8 __attribute__((ext_vector_type(8)));
typedef float f32x4 __attribute__((ext_vector_type(4)));
typedef float f32x16 __attribute__((ext_vector_type(16)));
typedef __hip_bfloat16 bf16;
typedef unsigned int uint;

static constexpr int Bn = 4, Nn = 2048, Cn = 1024, Hn = 16, Dn = 64;
static constexpr float kEps = 1e-6f;

// async global->LDS 16B per lane (wave-uniform dest base + lane*16)
#define GLOAD_LDS16(gp, lp)                                                        \
  __builtin_amdgcn_global_load_lds(                                                \
      (const __attribute__((address_space(1))) unsigned int*)(gp),                 \
      (__attribute__((address_space(3))) unsigned int*)(lp), 16, 0, 0)

__device__ __forceinline__ float exp2_raw(float x) {  // v_exp_f32: D = 2^S0
  float r;
  asm("v_exp_f32 %0, %1" : "=v"(r) : "v"(x));
  return r;
}

// ---------------- f32 -> bf16 convert (4 elems/thread) ----------------
__global__ __launch_bounds__(256) void cvt_kernel(const float* __restrict__ in,
                                                  bf16* __restrict__ out, int n4) {
  int i = blockIdx.x * 256 + threadIdx.x;
  if (i >= n4) return;
  const float4 v = reinterpret_cast<const float4*>(in)[i];
  bf16 t[4];
  t[0] = __float2bfloat16(v.x); t[1] = __float2bfloat16(v.y);
  t[2] = __float2bfloat16(v.z); t[3] = __float2bfloat16(v.w);
  reinterpret_cast<uint2*>(out)[i] = *reinterpret_cast<const uint2*>(t);
}

// ---------------- bf16 GEMM (m97 structure), C = A(MxK) * B(NxK)^T ----------
template <int EPI>
__global__ __launch_bounds__(256) void gemm_bt(
    const bf16* __restrict__ A, const bf16* __restrict__ Bw,
    float* __restrict__ Cf, bf16* __restrict__ q_raw, bf16* __restrict__ k_raw,
    bf16* __restrict__ v_buf, int N, int K) {
  __shared__ __align__(16) bf16 As[128 * 64];
  __shared__ __align__(16) bf16 Bs[128 * 64];
  const int tid = threadIdx.x;
  const int lane = tid & 63, w = tid >> 6;
  const int wr = w >> 1, wc = w & 1;
  const int l15 = lane & 15, l4 = lane >> 4;
  const int m0 = blockIdx.y * 128, n0 = blockIdx.x * 128;
  f32x4 acc[4][4] = {};

  const int sr = tid >> 3, sc = (tid & 7) * 8;
  const bf16* const Ap = A + (size_t)(m0 + sr) * K + sc;
  const bf16* const Bp = Bw + (size_t)(n0 + sr) * K + sc;
  char* const asd = (char*)As + tid * 16;
  char* const bsd = (char*)Bs + tid * 16;

  for (int k0 = 0; k0 < K; k0 += 64) {
    __syncthreads();
#pragma unroll
    for (int c = 0; c < 4; ++c) {
      GLOAD_LDS16(Ap + (size_t)(c * 32) * K + k0, asd + c * 4096);
      GLOAD_LDS16(Bp + (size_t)(c * 32) * K + k0, bsd + c * 4096);
    }
    __syncthreads();
#pragma unroll
    for (int kc = 0; kc < 2; ++kc) {
      bf16x8 af[4], bfr[4];
#pragma unroll
      for (int mi = 0; mi < 4; ++mi)
        af[mi] = *reinterpret_cast<const bf16x8*>(
            (const char*)As + (wr * 64 + mi * 16 + l15) * 128 + kc * 64 + l4 * 16);
#pragma unroll
      for (int ni = 0; ni < 4; ++ni)
        bfr[ni] = *reinterpret_cast<const bf16x8*>(
            (const char*)Bs + (wc * 64 + ni * 16 + l15) * 128 + kc * 64 + l4 * 16);
#pragma unroll
      for (int mi = 0; mi < 4; ++mi)
#pragma unroll
        for (int ni = 0; ni < 4; ++ni)
          acc[mi][ni] =
              __builtin_amdgcn_mfma_f32_16x16x32_bf16(af[mi], bfr[ni], acc[mi][ni], 0, 0, 0);
    }
  }

#pragma unroll
  for (int mi = 0; mi < 4; ++mi)
#pragma unroll
    for (int ni = 0; ni < 4; ++ni)
#pragma unroll
      for (int r = 0; r < 4; ++r) {
        const int row = m0 + wr * 64 + mi * 16 + l4 * 4 + r;
        const int col = n0 + wc * 64 + ni * 16 + l15;
        const float v = acc[mi][ni][r];
        if (EPI == 0) {
          const int which = col >> 10, hh = (col >> 6) & 15, d = col & 63;
          const int b = row >> 11, n = row & (Nn - 1);
          const size_t idx = (((size_t)b * Hn + hh) * Nn + n) * Dn + d;
          const bf16 val = __float2bfloat16(v);
          if (which == 0) q_raw[idx] = val;
          else if (which == 1) k_raw[idx] = val;
          else v_buf[idx] = val;
        } else {
          Cf[(size_t)row * N + col] = v;
        }
      }
}

// ---------------- RMSNorm + RoPE on q,k (in place), wave per row ----------------
// q pre-scaled by D^-0.5 * log2(e): flash softmax runs natively in exp2 domain.
__global__ __launch_bounds__(256) void norm_rope(bf16* __restrict__ q_raw,
                                                 bf16* __restrict__ k_raw,
                                                 const float* __restrict__ cosb,
                                                 const float* __restrict__ sinb,
                                                 const float* __restrict__ wq,
                                                 const float* __restrict__ wk) {
  const int row = blockIdx.x * 4 + (threadIdx.x >> 6);  // (b*H+h)*N + n
  const int lane = threadIdx.x & 63;
  const int n = row & (Nn - 1);
  const size_t base = (size_t)row * Dn + lane;
  const float c = cosb[n * Dn + lane], s = sinb[n * Dn + lane];
  float q = __bfloat162float(q_raw[base]);
  float k = __bfloat162float(k_raw[base]);
  float sq = q * q, sk = k * k;
#pragma unroll
  for (int off = 32; off >= 1; off >>= 1) {
    sq += __shfl_xor(sq, off);
    sk += __shfl_xor(sk, off);
  }
  const float rq = rsqrtf(sq * (1.f / Dn) + kEps) * wq[lane];
  const float rk = rsqrtf(sk * (1.f / Dn) + kEps) * wk[lane];
  const float qn = q * rq, kn = k * rk;
  const float qp = __shfl_xor(qn, 32), kp = __shfl_xor(kn, 32);
  const float sgn = (lane < 32) ? -1.f : 1.f;
  const float kQScale = 0.125f * 1.44269504088896340f;  // D^-0.5 * log2(e)
  q_raw[base] = __float2bfloat16((qn * c + sgn * qp * s) * kQScale);
  k_raw[base] = __float2bfloat16(kn * c + sgn * kp * s);
}

// ---------------- flash attention v6 = v4 structure + exp2 softmax ----------
// launch_bounds(256,3): the live set (Ot 32 + S 32 + qf 16 + wv 8 + staging)
// needs the 170-reg budget. (256,4)'s 128-reg cap spills ~0.3 GB/dispatch
// (measured r3, re-measured r5) — do NOT tighten this again.
__global__ __launch_bounds__(256, 3) void flash_attn(
    const bf16* __restrict__ Qb, const bf16* __restrict__ Kb,
    const bf16* __restrict__ Vb, bf16* __restrict__ Ob) {
  __shared__ __align__(16) char KsB[2][64 * 128];  // K[k][d], swz ((k&7)<<4)
  __shared__ __align__(16) char VtB[2][64 * 128];  // V^T[d][k], swz ((((d>>3)^d)&7)<<4)
  const int bh = blockIdx.y;
  const int q0 = blockIdx.x * 128;
  const int tid = threadIdx.x, lane = tid & 63, w = tid >> 6;
  const int l31 = lane & 31, hi = lane >> 5;
  const bf16* Qp = Qb + (size_t)bh * Nn * Dn;
  const bf16* Kp = Kb + (size_t)bh * Nn * Dn;
  const bf16* Vp = Vb + (size_t)bh * Nn * Dn;

  const int qrow = q0 + w * 32 + l31;
  bf16x8 qf[4];
#pragma unroll
  for (int dm = 0; dm < 4; ++dm)
    qf[dm] = *reinterpret_cast<const bf16x8*>(&Qp[(size_t)qrow * Dn + dm * 16 + hi * 8]);

  f32x16 Ot0 = {}, Ot1 = {};
  float m_r = -1e30f, l_r = 0.f;  // m_r in exp2 units

  const int skk = tid >> 3, sd0 = (tid & 7) * 8;
  const int swzK = (skk & 7) << 4;
  const int srcKe = (((sd0 * 2) ^ swzK) >> 1);  // pre-swizzled source col (elems)

  auto stage_v = [&](char* Vn, const uint4& a, const uint4& b) {
    const uint wa[4] = {a.x, a.y, a.z, a.w}, wb[4] = {b.x, b.y, b.z, b.w};
#pragma unroll
    for (int j = 0; j < 8; ++j) {
      const int d = sd0 + j;
      const int swz = (((d >> 3) ^ d) & 7) << 4;
      const unsigned short va = (j & 1) ? (unsigned short)(wa[j >> 1] >> 16)
                                        : (unsigned short)(wa[j >> 1] & 0xffff);
      const unsigned short vb2 = (j & 1) ? (unsigned short)(wb[j >> 1] >> 16)
                                         : (unsigned short)(wb[j >> 1] & 0xffff);
      *reinterpret_cast<unsigned short*>(Vn + d * 128 + ((skk * 2) ^ swz)) = va;
      *reinterpret_cast<unsigned short*>(Vn + d * 128 + ((skk * 2 + 64) ^ swz)) = vb2;
    }
  };

  GLOAD_LDS16(Kp + (size_t)skk * Dn + srcKe, KsB[0] + tid * 16);
  GLOAD_LDS16(Kp + (size_t)(skk + 32) * Dn + srcKe, KsB[0] + tid * 16 + 4096);
  {
    uint4 cva = *reinterpret_cast<const uint4*>(&Vp[(size_t)skk * Dn + sd0]);
    uint4 cvb = *reinterpret_cast<const uint4*>(&Vp[(size_t)(skk + 32) * Dn + sd0]);
    stage_v(VtB[0], cva, cvb);
  }
  uint4 nva = *reinterpret_cast<const uint4*>(&Vp[(size_t)(64 + skk) * Dn + sd0]);
  uint4 nvb = *reinterpret_cast<const uint4*>(&Vp[(size_t)(96 + skk) * Dn + sd0]);
  __syncthreads();

  const int swzk_rd = (l31 & 7) << 4;
  int cur = 0;
  for (int k0 = 0; k0 < Nn; k0 += 64) {
    const char* Kc = KsB[cur];
    const char* Vc = VtB[cur];

    if (k0 + 64 < Nn) {
      GLOAD_LDS16(Kp + (size_t)(k0 + 64 + skk) * Dn + srcKe, KsB[cur ^ 1] + tid * 16);
      GLOAD_LDS16(Kp + (size_t)(k0 + 96 + skk) * Dn + srcKe, KsB[cur ^ 1] + tid * 16 + 4096);
      stage_v(VtB[cur ^ 1], nva, nvb);
      if (k0 + 128 < Nn) {
        nva = *reinterpret_cast<const uint4*>(&Vp[(size_t)(k0 + 128 + skk) * Dn + sd0]);
        nvb = *reinterpret_cast<const uint4*>(&Vp[(size_t)(k0 + 160 + skk) * Dn + sd0]);
      }
    }

    // ---- S^T = K · Q^T : 8 MFMAs ----
    f32x16 S0 = {}, S1 = {};
    __builtin_amdgcn_s_setprio(1);
#pragma unroll
    for (int dm = 0; dm < 4; ++dm) {
      bf16x8 kf = *reinterpret_cast<const bf16x8*>(
          Kc + l31 * 128 + ((dm * 32 + hi * 16) ^ swzk_rd));
      S0 = __builtin_amdgcn_mfma_f32_32x32x16_bf16(kf, qf[dm], S0, 0, 0, 0);
    }
#pragma unroll
    for (int dm = 0; dm < 4; ++dm) {
      bf16x8 kf = *reinterpret_cast<const bf16x8*>(
          Kc + (32 + l31) * 128 + ((dm * 32 + hi * 16) ^ swzk_rd));
      S1 = __builtin_amdgcn_mfma_f32_32x32x16_bf16(kf, qf[dm], S1, 0, 0, 0);
    }
    __builtin_amdgcn_s_setprio(0);

    // ---- online softmax in exp2 domain, lane-local (q = l31) ----
    f32x16 tm;
#pragma unroll
    for (int i = 0; i < 16; ++i) tm[i] = fmaxf(S0[i], S1[i]);
#pragma unroll
    for (int i = 0; i < 8; ++i) tm[i] = fmaxf(tm[i], tm[i + 8]);
#pragma unroll
    for (int i = 0; i < 4; ++i) tm[i] = fmaxf(tm[i], tm[i + 4]);
    float mx = fmaxf(fmaxf(tm[0], tm[1]), fmaxf(tm[2], tm[3]));
    const float full = fmaxf(mx, __shfl_xor(mx, 32));
    if (__any(full > m_r + 8.f)) {  // defer-max (T13); P bounded by 2^8
      const float mnew = fmaxf(m_r, full);
      const float al = exp2_raw(m_r - mnew);
#pragma unroll
      for (int i = 0; i < 16; ++i) { Ot0[i] *= al; Ot1[i] *= al; }
      l_r *= al;
      m_r = mnew;
    }
#pragma unroll
    for (int i = 0; i < 16; ++i) S0[i] = exp2_raw(S0[i] - m_r);
#pragma unroll
    for (int i = 0; i < 16; ++i) S1[i] = exp2_raw(S1[i] - m_r);
    float ps = 0.f;
    uint wv[2][8];
#pragma unroll
    for (int kc = 0; kc < 2; ++kc) {
      const f32x16& P = kc ? S1 : S0;
#pragma unroll
      for (int c = 0; c < 2; ++c) {
        ps += ((P[8 * c + 0] + P[8 * c + 1]) + (P[8 * c + 2] + P[8 * c + 3])) +
              ((P[8 * c + 4] + P[8 * c + 5]) + (P[8 * c + 6] + P[8 * c + 7]));
        uint w0, w1, w2, w3;
        asm("v_cvt_pk_bf16_f32 %0, %1, %2" : "=v"(w0) : "v"(P[8 * c + 0]), "v"(P[8 * c + 1]));
        asm("v_cvt_pk_bf16_f32 %0, %1, %2" : "=v"(w1) : "v"(P[8 * c + 2]), "v"(P[8 * c + 3]));
        asm("v_cvt_pk_bf16_f32 %0, %1, %2" : "=v"(w2) : "v"(P[8 * c + 4]), "v"(P[8 * c + 5]));
        asm("v_cvt_pk_bf16_f32 %0, %1, %2" : "=v"(w3) : "v"(P[8 * c + 6]), "v"(P[8 * c + 7]));
        asm("v_permlane32_swap_b32 %0, %1" : "+v"(w0), "+v"(w2));
        asm("v_permlane32_swap_b32 %0, %1" : "+v"(w1), "+v"(w3));
        wv[kc][c * 4 + 0] = w0; wv[kc][c * 4 + 1] = w1;
        wv[kc][c * 4 + 2] = w2; wv[kc][c * 4 + 3] = w3;
      }
    }
    ps += __shfl_xor(ps, 32);
    l_r += ps;

    // ---- O^T += V^T · P^T : 8 MFMAs ----
    __builtin_amdgcn_s_setprio(1);
#pragma unroll
    for (int s = 0; s < 4; ++s) {
      const uint4 uu = {wv[s >> 1][(s & 1) * 4 + 0], wv[s >> 1][(s & 1) * 4 + 1],
                        wv[s >> 1][(s & 1) * 4 + 2], wv[s >> 1][(s & 1) * 4 + 3]};
      const bf16x8 pa = __builtin_bit_cast(bf16x8, uu);
      {
        const int d = l31;
        const int swz = (((d >> 3) ^ d) & 7) << 4;
        bf16x8 vf = *reinterpret_cast<const bf16x8*>(Vc + d * 128 + ((s * 32 + hi * 16) ^ swz));
        Ot0 = __builtin_amdgcn_mfma_f32_32x32x16_bf16(vf, pa, Ot0, 0, 0, 0);
      }
      {
        const int d = 32 + l31;
        const int swz = (((d >> 3) ^ d) & 7) << 4;
        bf16x8 vf = *reinterpret_cast<const bf16x8*>(Vc + d * 128 + ((s * 32 + hi * 16) ^ swz));
        Ot1 = __builtin_amdgcn_mfma_f32_32x32x16_bf16(vf, pa, Ot1, 0, 0, 0);
      }
    }
    __builtin_amdgcn_s_setprio(0);

    __syncthreads();
    cur ^= 1;
  }

  // ---- epilogue ----
  const float inv = 1.f / l_r;
  const int b = bh >> 4, h = bh & 15;
#pragma unroll
  for (int dc = 0; dc < 2; ++dc)
#pragma unroll
    for (int a2 = 0; a2 < 4; ++a2) {
      const f32x16& O = dc ? Ot1 : Ot0;
      unsigned short u0 = __bfloat16_as_ushort(__float2bfloat16(O[a2 * 4 + 0] * inv));
      unsigned short u1 = __bfloat16_as_ushort(__float2bfloat16(O[a2 * 4 + 1] * inv));
      unsigned short u2 = __bfloat16_as_ushort(__float2bfloat16(O[a2 * 4 + 2] * inv));
      unsigned short u3 = __bfloat16_as_ushort(__float2bfloat16(O[a2 * 4 + 3] * inv));
      uint2 pk;
      pk.x = (uint)u0 | ((uint)u1 << 16);
      pk.y = (uint)u2 | ((uint)u3 << 16);
      const int col = h * 64 + dc * 32 + a2 * 8 + hi * 4;
      *reinterpret_cast<uint2*>(&Ob[((size_t)(b * Nn + qrow)) * Cn + col]) = pk;
    }
}

extern "C" void kernel_launch(void* const* d_in, const int* in_sizes, int n_in,
                              void* d_out, int out_size, void* d_ws, size_t ws_size,
                              hipStream_t stream) {
  const float* hs   = (const float*)d_in[0];
  const float* cosb = (const float*)d_in[1];
  const float* sinb = (const float*)d_in[2];
  const float* qkvw = (const float*)d_in[3];
  const float* outw = (const float*)d_in[4];
  const float* nqw  = (const float*)d_in[5];
  const float* nkw  = (const float*)d_in[6];
  float* out = (float*)d_out;

  char* ws = (char*)d_ws;
  size_t off = 0;
  bf16* hs_b   = (bf16*)(ws + off); off += (size_t)Bn * Nn * Cn * 2;
  bf16* qkvw_b = (bf16*)(ws + off); off += (size_t)3 * Cn * Cn * 2;
  bf16* outw_b = (bf16*)(ws + off); off += (size_t)Cn * Cn * 2;
  bf16* q_raw  = (bf16*)(ws + off); off += (size_t)Bn * Hn * Nn * Dn * 2;
  bf16* k_raw  = (bf16*)(ws + off); off += (size_t)Bn * Hn * Nn * Dn * 2;
  bf16* v_buf  = (bf16*)(ws + off); off += (size_t)Bn * Hn * Nn * Dn * 2;
  bf16* attn   = (bf16*)(ws + off); off += (size_t)Bn * Nn * Cn * 2;

  cvt_kernel<<<(Bn * Nn * Cn / 4 + 255) / 256, 256, 0, stream>>>(hs, hs_b, Bn * Nn * Cn / 4);
  cvt_kernel<<<(3 * Cn * Cn / 4 + 255) / 256, 256, 0, stream>>>(qkvw, qkvw_b, 3 * Cn * Cn / 4);
  cvt_kernel<<<(Cn * Cn / 4 + 255) / 256, 256, 0, stream>>>(outw, outw_b, Cn * Cn / 4);

  gemm_bt<0><<<dim3(3 * Cn / 128, Bn * Nn / 128), 256, 0, stream>>>(
      hs_b, qkvw_b, nullptr, q_raw, k_raw, v_buf, 3 * Cn, Cn);

  norm_rope<<<(Bn * Hn * Nn) / 4, 256, 0, stream>>>(q_raw, k_raw, cosb, sinb, nqw, nkw);

  flash_attn<<<dim3(Nn / 128, Bn * Hn), 256, 0, stream>>>(q_raw, k_raw, v_buf, attn);

  gemm_bt<1><<<dim3(Cn / 128, Bn * Nn / 128), 256, 0, stream>>>(
      attn, outw_b, out, nullptr, nullptr, nullptr, Cn, Cn);
}

// Round 7
// 236.891 us; speedup vs baseline: 1.6286x; 1.0884x over previous
//
#include <hip/hip_runtime.h>
#include <hip/hip_bf16.h>

typedef short bf16x8 __attribute__((ext_vector_type(8)));
typedef float f32x4 __attribute__((ext_vector_type(4)));
typedef float f32x16 __attribute__((ext_vector_type(16)));
typedef __hip_bfloat16 bf16;
typedef unsigned int uint;

static constexpr int Bn = 4, Nn = 2048, Cn = 1024, Hn = 16, Dn = 64;
static constexpr float kEps = 1e-6f;
static constexpr float kQScale = 0.125f * 1.44269504088896340f;  // D^-0.5 * log2(e)

// async global->LDS 16B per lane (wave-uniform dest base + lane*16)
#define GLOAD_LDS16(gp, lp)                                                        \
  __builtin_amdgcn_global_load_lds(                                                \
      (const __attribute__((address_space(1))) unsigned int*)(gp),                 \
      (__attribute__((address_space(3))) unsigned int*)(lp), 16, 0, 0)

__device__ __forceinline__ float exp2_raw(float x) {  // v_exp_f32: D = 2^S0
  float r;
  asm("v_exp_f32 %0, %1" : "=v"(r) : "v"(x));
  return r;
}

// ---------------- f32 -> bf16 convert (4 elems/thread) ----------------
__global__ __launch_bounds__(256) void cvt_kernel(const float* __restrict__ in,
                                                  bf16* __restrict__ out, int n4) {
  int i = blockIdx.x * 256 + threadIdx.x;
  if (i >= n4) return;
  const float4 v = reinterpret_cast<const float4*>(in)[i];
  bf16 t[4];
  t[0] = __float2bfloat16(v.x); t[1] = __float2bfloat16(v.y);
  t[2] = __float2bfloat16(v.z); t[3] = __float2bfloat16(v.w);
  reinterpret_cast<uint2*>(out)[i] = *reinterpret_cast<const uint2*>(t);
}

// ---------------- bf16 GEMM (m97 structure), C = A(MxK) * B(NxK)^T ----------
// EPI 0: fused epilogue — RMSNorm+RoPE on q/k fragments (each wave's 64-col
// block is exactly one head), scatter bf16 to q_raw/k_raw/v_buf [B][H][N][D].
// EPI 1: plain f32 store.
template <int EPI>
__global__ __launch_bounds__(256) void gemm_bt(
    const bf16* __restrict__ A, const bf16* __restrict__ Bw,
    float* __restrict__ Cf, bf16* __restrict__ q_raw, bf16* __restrict__ k_raw,
    bf16* __restrict__ v_buf, const float* __restrict__ cosb,
    const float* __restrict__ sinb, const float* __restrict__ nqw,
    const float* __restrict__ nkw, int N, int K) {
  __shared__ __align__(16) bf16 As[128 * 64];
  __shared__ __align__(16) bf16 Bs[128 * 64];
  const int tid = threadIdx.x;
  const int lane = tid & 63, w = tid >> 6;
  const int wr = w >> 1, wc = w & 1;
  const int l15 = lane & 15, l4 = lane >> 4;
  const int m0 = blockIdx.y * 128, n0 = blockIdx.x * 128;
  f32x4 acc[4][4] = {};

  const int sr = tid >> 3, sc = (tid & 7) * 8;
  const bf16* const Ap = A + (size_t)(m0 + sr) * K + sc;
  const bf16* const Bp = Bw + (size_t)(n0 + sr) * K + sc;
  char* const asd = (char*)As + tid * 16;
  char* const bsd = (char*)Bs + tid * 16;

  for (int k0 = 0; k0 < K; k0 += 64) {
    __syncthreads();
#pragma unroll
    for (int c = 0; c < 4; ++c) {
      GLOAD_LDS16(Ap + (size_t)(c * 32) * K + k0, asd + c * 4096);
      GLOAD_LDS16(Bp + (size_t)(c * 32) * K + k0, bsd + c * 4096);
    }
    __syncthreads();
#pragma unroll
    for (int kc = 0; kc < 2; ++kc) {
      bf16x8 af[4], bfr[4];
#pragma unroll
      for (int mi = 0; mi < 4; ++mi)
        af[mi] = *reinterpret_cast<const bf16x8*>(
            (const char*)As + (wr * 64 + mi * 16 + l15) * 128 + kc * 64 + l4 * 16);
#pragma unroll
      for (int ni = 0; ni < 4; ++ni)
        bfr[ni] = *reinterpret_cast<const bf16x8*>(
            (const char*)Bs + (wc * 64 + ni * 16 + l15) * 128 + kc * 64 + l4 * 16);
#pragma unroll
      for (int mi = 0; mi < 4; ++mi)
#pragma unroll
        for (int ni = 0; ni < 4; ++ni)
          acc[mi][ni] =
              __builtin_amdgcn_mfma_f32_16x16x32_bf16(af[mi], bfr[ni], acc[mi][ni], 0, 0, 0);
    }
  }

  if (EPI == 1) {
#pragma unroll
    for (int mi = 0; mi < 4; ++mi)
#pragma unroll
      for (int ni = 0; ni < 4; ++ni)
#pragma unroll
        for (int r = 0; r < 4; ++r) {
          const int row = m0 + wr * 64 + mi * 16 + l4 * 4 + r;
          const int col = n0 + wc * 64 + ni * 16 + l15;
          Cf[(size_t)row * N + col] = acc[mi][ni][r];
        }
    return;
  }

  // ---- EPI 0: fused epilogue ----
  const int colbase = n0 + wc * 64;       // wave-uniform
  const int which = colbase >> 10;        // 0:q 1:k 2:v
  const int hh = (colbase >> 6) & 15;
  if (which == 2) {
#pragma unroll
    for (int mi = 0; mi < 4; ++mi)
#pragma unroll
      for (int r = 0; r < 4; ++r) {
        const int row = m0 + wr * 64 + mi * 16 + l4 * 4 + r;
        const int b = row >> 11, n = row & (Nn - 1);
#pragma unroll
        for (int ni = 0; ni < 4; ++ni) {
          const int d = ni * 16 + l15;
          const size_t idx = (((size_t)b * Hn + hh) * Nn + n) * Dn + d;
          v_buf[idx] = __float2bfloat16(acc[mi][ni][r]);
        }
      }
    return;
  }
  // q or k: RMSNorm over the head's 64 d (l15-group shfl reduce) + RoPE.
  const float* const wgt = which ? nkw : nqw;
  bf16* const dst = which ? k_raw : q_raw;
  float wv4[4];
#pragma unroll
  for (int ni = 0; ni < 4; ++ni) wv4[ni] = wgt[ni * 16 + l15];
#pragma unroll
  for (int mi = 0; mi < 4; ++mi)
#pragma unroll
    for (int r = 0; r < 4; ++r) {
      const int row = m0 + wr * 64 + mi * 16 + l4 * 4 + r;
      const int b = row >> 11, n = row & (Nn - 1);
      float x0 = acc[mi][0][r], x1 = acc[mi][1][r], x2 = acc[mi][2][r], x3 = acc[mi][3][r];
      float ss = x0 * x0 + x1 * x1 + x2 * x2 + x3 * x3;
      ss += __shfl_xor(ss, 1);
      ss += __shfl_xor(ss, 2);
      ss += __shfl_xor(ss, 4);
      ss += __shfl_xor(ss, 8);
      const float rinv = rsqrtf(ss * (1.f / Dn) + kEps);
      float nx[4] = {x0 * rinv * wv4[0], x1 * rinv * wv4[1], x2 * rinv * wv4[2],
                     x3 * rinv * wv4[3]};
#pragma unroll
      for (int ni = 0; ni < 4; ++ni) {
        const int d = ni * 16 + l15;
        const float c = cosb[n * Dn + d], s = sinb[n * Dn + d];
        const float sgn = (ni < 2) ? -1.f : 1.f;
        float val = nx[ni] * c + sgn * nx[ni ^ 2] * s;
        if (which == 0) val *= kQScale;
        const size_t idx = (((size_t)b * Hn + hh) * Nn + n) * Dn + d;
        dst[idx] = __float2bfloat16(val);
      }
    }
}

// ---------------- flash attention v7: KVBLK=32, 16KB LDS ----------
// Swapped-operand in-register softmax (q = lane&31). K[32][64] bf16 in LDS
// (128B rows, swz (k&7)<<4, staged via global_load_lds w/ pre-swizzled src);
// V^T[64 d][32 k] (64B rows, slot swz ((d>>1)^(d>>3))&3 — conflict-free b128
// reads, <=4-way 2B staging writes). Double-buffered, 1 barrier/iter.
// launch_bounds(256,3): 170-reg budget; do NOT tighten (r3/r5 spilled).
__global__ __launch_bounds__(256, 3) void flash_attn(
    const bf16* __restrict__ Qb, const bf16* __restrict__ Kb,
    const bf16* __restrict__ Vb, bf16* __restrict__ Ob) {
  __shared__ __align__(16) char KsB[2][32 * 128];  // 8 KB
  __shared__ __align__(16) char VtB[2][64 * 64];   // 8 KB
  const int bh = blockIdx.y;
  const int q0 = blockIdx.x * 128;
  const int tid = threadIdx.x, lane = tid & 63, w = tid >> 6;
  const int l31 = lane & 31, hi = lane >> 5;
  const bf16* Qp = Qb + (size_t)bh * Nn * Dn;
  const bf16* Kp = Kb + (size_t)bh * Nn * Dn;
  const bf16* Vp = Vb + (size_t)bh * Nn * Dn;

  const int qrow = q0 + w * 32 + l31;
  bf16x8 qf[4];
#pragma unroll
  for (int dm = 0; dm < 4; ++dm)
    qf[dm] = *reinterpret_cast<const bf16x8*>(&Qp[(size_t)qrow * Dn + dm * 16 + hi * 8]);

  f32x16 Ot0 = {}, Ot1 = {};
  float m_r = -1e30f, l_r = 0.f;  // exp2 domain

  // staging: thread covers K/V row skk (0..31), d-cols sd0..sd0+7
  const int skk = tid >> 3, sd0 = (tid & 7) * 8;
  const int srcKe = (((sd0 * 2) ^ ((skk & 7) << 4)) >> 1);  // pre-swizzled src col

  auto stage_v = [&](char* Vn, const uint4& a) {
    const uint wa[4] = {a.x, a.y, a.z, a.w};
#pragma unroll
    for (int j = 0; j < 8; ++j) {
      const int d = sd0 + j;
      const int xs = (((d >> 1) ^ (d >> 3)) & 3) << 4;
      const unsigned short va = (j & 1) ? (unsigned short)(wa[j >> 1] >> 16)
                                        : (unsigned short)(wa[j >> 1] & 0xffff);
      *reinterpret_cast<unsigned short*>(Vn + d * 64 + ((skk * 2) ^ xs)) = va;
    }
  };

  // prologue: tile0 K via DMA, tile0 V staged, tile1 V into reg
  GLOAD_LDS16(Kp + (size_t)skk * Dn + srcKe, KsB[0] + tid * 16);
  {
    uint4 cv = *reinterpret_cast<const uint4*>(&Vp[(size_t)skk * Dn + sd0]);
    stage_v(VtB[0], cv);
  }
  uint4 nv = *reinterpret_cast<const uint4*>(&Vp[(size_t)(32 + skk) * Dn + sd0]);
  __syncthreads();

  const int swzk_rd = (l31 & 7) << 4;
  const int xs0 = ((((l31) >> 1) ^ ((l31) >> 3)) & 3) << 4;
  const int xs1 = ((((32 + l31) >> 1) ^ ((32 + l31) >> 3)) & 3) << 4;
  int cur = 0;
  for (int k0 = 0; k0 < Nn; k0 += 32) {
    const char* Kc = KsB[cur];
    const char* Vc = VtB[cur];

    // prefetch tile k0+32; issue V load for k0+64
    if (k0 + 32 < Nn) {
      GLOAD_LDS16(Kp + (size_t)(k0 + 32 + skk) * Dn + srcKe, KsB[cur ^ 1] + tid * 16);
      stage_v(VtB[cur ^ 1], nv);
      if (k0 + 64 < Nn)
        nv = *reinterpret_cast<const uint4*>(&Vp[(size_t)(k0 + 64 + skk) * Dn + sd0]);
    }

    // ---- S^T = K · Q^T : 4 MFMAs ----
    f32x16 S0 = {};
    __builtin_amdgcn_s_setprio(1);
#pragma unroll
    for (int dm = 0; dm < 4; ++dm) {
      bf16x8 kf = *reinterpret_cast<const bf16x8*>(
          Kc + l31 * 128 + ((dm * 32 + hi * 16) ^ swzk_rd));
      S0 = __builtin_amdgcn_mfma_f32_32x32x16_bf16(kf, qf[dm], S0, 0, 0, 0);
    }
    __builtin_amdgcn_s_setprio(0);

    // ---- online softmax (exp2 domain), lane-local ----
    float tm8[8];
#pragma unroll
    for (int i = 0; i < 8; ++i) tm8[i] = fmaxf(S0[i], S0[i + 8]);
#pragma unroll
    for (int i = 0; i < 4; ++i) tm8[i] = fmaxf(tm8[i], tm8[i + 4]);
    float mx = fmaxf(fmaxf(tm8[0], tm8[1]), fmaxf(tm8[2], tm8[3]));
    const float full = fmaxf(mx, __shfl_xor(mx, 32));
    if (__any(full > m_r + 8.f)) {  // defer-max (T13)
      const float mnew = fmaxf(m_r, full);
      const float al = exp2_raw(m_r - mnew);
#pragma unroll
      for (int i = 0; i < 16; ++i) { Ot0[i] *= al; Ot1[i] *= al; }
      l_r *= al;
      m_r = mnew;
    }
#pragma unroll
    for (int i = 0; i < 16; ++i) S0[i] = exp2_raw(S0[i] - m_r);
    float ps = 0.f;
    uint wv[8];
#pragma unroll
    for (int c = 0; c < 2; ++c) {
      ps += ((S0[8 * c + 0] + S0[8 * c + 1]) + (S0[8 * c + 2] + S0[8 * c + 3])) +
            ((S0[8 * c + 4] + S0[8 * c + 5]) + (S0[8 * c + 6] + S0[8 * c + 7]));
      uint w0, w1, w2, w3;
      asm("v_cvt_pk_bf16_f32 %0, %1, %2" : "=v"(w0) : "v"(S0[8 * c + 0]), "v"(S0[8 * c + 1]));
      asm("v_cvt_pk_bf16_f32 %0, %1, %2" : "=v"(w1) : "v"(S0[8 * c + 2]), "v"(S0[8 * c + 3]));
      asm("v_cvt_pk_bf16_f32 %0, %1, %2" : "=v"(w2) : "v"(S0[8 * c + 4]), "v"(S0[8 * c + 5]));
      asm("v_cvt_pk_bf16_f32 %0, %1, %2" : "=v"(w3) : "v"(S0[8 * c + 6]), "v"(S0[8 * c + 7]));
      asm("v_permlane32_swap_b32 %0, %1" : "+v"(w0), "+v"(w2));
      asm("v_permlane32_swap_b32 %0, %1" : "+v"(w1), "+v"(w3));
      wv[c * 4 + 0] = w0; wv[c * 4 + 1] = w1;
      wv[c * 4 + 2] = w2; wv[c * 4 + 3] = w3;
    }
    ps += __shfl_xor(ps, 32);
    l_r += ps;

    // ---- O^T += V^T · P^T : 4 MFMAs ----
    __builtin_amdgcn_s_setprio(1);
#pragma unroll
    for (int s = 0; s < 2; ++s) {
      const uint4 uu = {wv[s * 4 + 0], wv[s * 4 + 1], wv[s * 4 + 2], wv[s * 4 + 3]};
      const bf16x8 pa = __builtin_bit_cast(bf16x8, uu);
      bf16x8 vf0 = *reinterpret_cast<const bf16x8*>(
          Vc + l31 * 64 + ((s * 32 + hi * 16) ^ xs0));
      Ot0 = __builtin_amdgcn_mfma_f32_32x32x16_bf16(vf0, pa, Ot0, 0, 0, 0);
      bf16x8 vf1 = *reinterpret_cast<const bf16x8*>(
          Vc + (32 + l31) * 64 + ((s * 32 + hi * 16) ^ xs1));
      Ot1 = __builtin_amdgcn_mfma_f32_32x32x16_bf16(vf1, pa, Ot1, 0, 0, 0);
    }
    __builtin_amdgcn_s_setprio(0);

    __syncthreads();
    cur ^= 1;
  }

  // ---- epilogue ----
  const float inv = 1.f / l_r;
  const int b = bh >> 4, h = bh & 15;
#pragma unroll
  for (int dc = 0; dc < 2; ++dc)
#pragma unroll
    for (int a2 = 0; a2 < 4; ++a2) {
      const f32x16& O = dc ? Ot1 : Ot0;
      unsigned short u0 = __bfloat16_as_ushort(__float2bfloat16(O[a2 * 4 + 0] * inv));
      unsigned short u1 = __bfloat16_as_ushort(__float2bfloat16(O[a2 * 4 + 1] * inv));
      unsigned short u2 = __bfloat16_as_ushort(__float2bfloat16(O[a2 * 4 + 2] * inv));
      unsigned short u3 = __bfloat16_as_ushort(__float2bfloat16(O[a2 * 4 + 3] * inv));
      uint2 pk;
      pk.x = (uint)u0 | ((uint)u1 << 16);
      pk.y = (uint)u2 | ((uint)u3 << 16);
      const int col = h * 64 + dc * 32 + a2 * 8 + hi * 4;
      *reinterpret_cast<uint2*>(&Ob[((size_t)(b * Nn + qrow)) * Cn + col]) = pk;
    }
}

extern "C" void kernel_launch(void* const* d_in, const int* in_sizes, int n_in,
                              void* d_out, int out_size, void* d_ws, size_t ws_size,
                              hipStream_t stream) {
  const float* hs   = (const float*)d_in[0];
  const float* cosb = (const float*)d_in[1];
  const float* sinb = (const float*)d_in[2];
  const float* qkvw = (const float*)d_in[3];
  const float* outw = (const float*)d_in[4];
  const float* nqw  = (const float*)d_in[5];
  const float* nkw  = (const float*)d_in[6];
  float* out = (float*)d_out;

  char* ws = (char*)d_ws;
  size_t off = 0;
  bf16* hs_b   = (bf16*)(ws + off); off += (size_t)Bn * Nn * Cn * 2;
  bf16* qkvw_b = (bf16*)(ws + off); off += (size_t)3 * Cn * Cn * 2;
  bf16* outw_b = (bf16*)(ws + off); off += (size_t)Cn * Cn * 2;
  bf16* q_raw  = (bf16*)(ws + off); off += (size_t)Bn * Hn * Nn * Dn * 2;
  bf16* k_raw  = (bf16*)(ws + off); off += (size_t)Bn * Hn * Nn * Dn * 2;
  bf16* v_buf  = (bf16*)(ws + off); off += (size_t)Bn * Hn * Nn * Dn * 2;
  bf16* attn   = (bf16*)(ws + off); off += (size_t)Bn * Nn * Cn * 2;

  cvt_kernel<<<(Bn * Nn * Cn / 4 + 255) / 256, 256, 0, stream>>>(hs, hs_b, Bn * Nn * Cn / 4);
  cvt_kernel<<<(3 * Cn * Cn / 4 + 255) / 256, 256, 0, stream>>>(qkvw, qkvw_b, 3 * Cn * Cn / 4);
  cvt_kernel<<<(Cn * Cn / 4 + 255) / 256, 256, 0, stream>>>(outw, outw_b, Cn * Cn / 4);

  // QKV projection + fused RMSNorm/RoPE epilogue
  gemm_bt<0><<<dim3(3 * Cn / 128, Bn * Nn / 128), 256, 0, stream>>>(
      hs_b, qkvw_b, nullptr, q_raw, k_raw, v_buf, cosb, sinb, nqw, nkw, 3 * Cn, Cn);

  flash_attn<<<dim3(Nn / 128, Bn * Hn), 256, 0, stream>>>(q_raw, k_raw, v_buf, attn);

  gemm_bt<1><<<dim3(Cn / 128, Bn * Nn / 128), 256, 0, stream>>>(
      attn, outw_b, out, nullptr, nullptr, nullptr, nullptr, nullptr, nullptr, nullptr,
      Cn, Cn);
}

// Round 8
// 235.256 us; speedup vs baseline: 1.6399x; 1.0069x over previous
//
#include <hip/hip_runtime.h>
#include <hip/hip_bf16.h>

typedef short bf16x8 __attribute__((ext_vector_type(8)));
typedef float f32x4 __attribute__((ext_vector_type(4)));
typedef float f32x16 __attribute__((ext_vector_type(16)));
typedef __hip_bfloat16 bf16;
typedef unsigned int uint;

static constexpr int Bn = 4, Nn = 2048, Cn = 1024, Hn = 16, Dn = 64;
static constexpr float kEps = 1e-6f;
static constexpr float kQScale = 0.125f * 1.44269504088896340f;  // D^-0.5 * log2(e)

// async global->LDS 16B per lane (wave-uniform dest base + lane*16)
#define GLOAD_LDS16(gp, lp)                                                        \
  __builtin_amdgcn_global_load_lds(                                                \
      (const __attribute__((address_space(1))) unsigned int*)(gp),                 \
      (__attribute__((address_space(3))) unsigned int*)(lp), 16, 0, 0)

__device__ __forceinline__ float exp2_raw(float x) {  // v_exp_f32: D = 2^S0
  float r;
  asm("v_exp_f32 %0, %1" : "=v"(r) : "v"(x));
  return r;
}

// ---------------- f32 -> bf16 convert (4 elems/thread) ----------------
__global__ __launch_bounds__(256) void cvt_kernel(const float* __restrict__ in,
                                                  bf16* __restrict__ out, int n4) {
  int i = blockIdx.x * 256 + threadIdx.x;
  if (i >= n4) return;
  const float4 v = reinterpret_cast<const float4*>(in)[i];
  bf16 t[4];
  t[0] = __float2bfloat16(v.x); t[1] = __float2bfloat16(v.y);
  t[2] = __float2bfloat16(v.z); t[3] = __float2bfloat16(v.w);
  reinterpret_cast<uint2*>(out)[i] = *reinterpret_cast<const uint2*>(t);
}

// ---------------- bf16 GEMM (m97 structure), C = A(MxK) * B(NxK)^T ----------
// 1D grid + XCD-slab swizzle: each XCD owns a contiguous group of n-columns;
// within it, consecutive blocks walk m-tiles down one column so the B column
// tile (256 KB) stays resident in that XCD's L2.
// EPI 0: fused RMSNorm+RoPE epilogue, scatter to q_raw/k_raw/v_buf.
// EPI 1: plain f32 store.
template <int EPI>
__global__ __launch_bounds__(256) void gemm_bt(
    const bf16* __restrict__ A, const bf16* __restrict__ Bw,
    float* __restrict__ Cf, bf16* __restrict__ q_raw, bf16* __restrict__ k_raw,
    bf16* __restrict__ v_buf, const float* __restrict__ cosb,
    const float* __restrict__ sinb, const float* __restrict__ nqw,
    const float* __restrict__ nkw, int nxt, int nyt, int N, int K) {
  __shared__ __align__(16) bf16 As[128 * 64];
  __shared__ __align__(16) bf16 Bs[128 * 64];
  const int tid = threadIdx.x;
  const int lane = tid & 63, w = tid >> 6;
  const int wr = w >> 1, wc = w & 1;
  const int l15 = lane & 15, l4 = lane >> 4;
  // XCD-slab swizzle (nxt % 8 == 0 for both call sites -> bijective)
  const int bid = blockIdx.x;
  const int xcd = bid & 7;
  const int kk2 = bid >> 3;
  const int ntile = xcd * (nxt >> 3) + kk2 / nyt;
  const int mtile = kk2 % nyt;
  const int m0 = mtile * 128, n0 = ntile * 128;
  f32x4 acc[4][4] = {};

  const int sr = tid >> 3, sc = (tid & 7) * 8;
  const bf16* const Ap = A + (size_t)(m0 + sr) * K + sc;
  const bf16* const Bp = Bw + (size_t)(n0 + sr) * K + sc;
  char* const asd = (char*)As + tid * 16;
  char* const bsd = (char*)Bs + tid * 16;

  for (int k0 = 0; k0 < K; k0 += 64) {
    __syncthreads();
#pragma unroll
    for (int c = 0; c < 4; ++c) {
      GLOAD_LDS16(Ap + (size_t)(c * 32) * K + k0, asd + c * 4096);
      GLOAD_LDS16(Bp + (size_t)(c * 32) * K + k0, bsd + c * 4096);
    }
    __syncthreads();
#pragma unroll
    for (int kc = 0; kc < 2; ++kc) {
      bf16x8 af[4], bfr[4];
#pragma unroll
      for (int mi = 0; mi < 4; ++mi)
        af[mi] = *reinterpret_cast<const bf16x8*>(
            (const char*)As + (wr * 64 + mi * 16 + l15) * 128 + kc * 64 + l4 * 16);
#pragma unroll
      for (int ni = 0; ni < 4; ++ni)
        bfr[ni] = *reinterpret_cast<const bf16x8*>(
            (const char*)Bs + (wc * 64 + ni * 16 + l15) * 128 + kc * 64 + l4 * 16);
#pragma unroll
      for (int mi = 0; mi < 4; ++mi)
#pragma unroll
        for (int ni = 0; ni < 4; ++ni)
          acc[mi][ni] =
              __builtin_amdgcn_mfma_f32_16x16x32_bf16(af[mi], bfr[ni], acc[mi][ni], 0, 0, 0);
    }
  }

  if (EPI == 1) {
#pragma unroll
    for (int mi = 0; mi < 4; ++mi)
#pragma unroll
      for (int ni = 0; ni < 4; ++ni)
#pragma unroll
        for (int r = 0; r < 4; ++r) {
          const int row = m0 + wr * 64 + mi * 16 + l4 * 4 + r;
          const int col = n0 + wc * 64 + ni * 16 + l15;
          Cf[(size_t)row * N + col] = acc[mi][ni][r];
        }
    return;
  }

  // ---- EPI 0: fused epilogue ----
  const int colbase = n0 + wc * 64;       // wave-uniform
  const int which = colbase >> 10;        // 0:q 1:k 2:v
  const int hh = (colbase >> 6) & 15;
  if (which == 2) {
#pragma unroll
    for (int mi = 0; mi < 4; ++mi)
#pragma unroll
      for (int r = 0; r < 4; ++r) {
        const int row = m0 + wr * 64 + mi * 16 + l4 * 4 + r;
        const int b = row >> 11, n = row & (Nn - 1);
#pragma unroll
        for (int ni = 0; ni < 4; ++ni) {
          const int d = ni * 16 + l15;
          const size_t idx = (((size_t)b * Hn + hh) * Nn + n) * Dn + d;
          v_buf[idx] = __float2bfloat16(acc[mi][ni][r]);
        }
      }
    return;
  }
  const float* const wgt = which ? nkw : nqw;
  bf16* const dst = which ? k_raw : q_raw;
  float wv4[4];
#pragma unroll
  for (int ni = 0; ni < 4; ++ni) wv4[ni] = wgt[ni * 16 + l15];
#pragma unroll
  for (int mi = 0; mi < 4; ++mi)
#pragma unroll
    for (int r = 0; r < 4; ++r) {
      const int row = m0 + wr * 64 + mi * 16 + l4 * 4 + r;
      const int b = row >> 11, n = row & (Nn - 1);
      float x0 = acc[mi][0][r], x1 = acc[mi][1][r], x2 = acc[mi][2][r], x3 = acc[mi][3][r];
      float ss = x0 * x0 + x1 * x1 + x2 * x2 + x3 * x3;
      ss += __shfl_xor(ss, 1);
      ss += __shfl_xor(ss, 2);
      ss += __shfl_xor(ss, 4);
      ss += __shfl_xor(ss, 8);
      const float rinv = rsqrtf(ss * (1.f / Dn) + kEps);
      float nx[4] = {x0 * rinv * wv4[0], x1 * rinv * wv4[1], x2 * rinv * wv4[2],
                     x3 * rinv * wv4[3]};
#pragma unroll
      for (int ni = 0; ni < 4; ++ni) {
        const int d = ni * 16 + l15;
        const float c = cosb[n * Dn + d], s = sinb[n * Dn + d];
        const float sgn = (ni < 2) ? -1.f : 1.f;
        float val = nx[ni] * c + sgn * nx[ni ^ 2] * s;
        if (which == 0) val *= kQScale;
        const size_t idx = (((size_t)b * Hn + hh) * Nn + n) * Dn + d;
        dst[idx] = __float2bfloat16(val);
      }
    }
}

// ---------------- flash attention v8: KVBLK=32, 16KB LDS, 4 blocks/CU -------
// r7 structure; launch_bounds(256,4) is safe NOW because the KVBLK=32 live
// set is ~56 arch VGPR + ~48 acc = ~104 < 128 (r7 measured VGPR_Count=56).
// If WRITE_SIZE balloons above ~17 MB -> spilling -> revert to (256,3).
__global__ __launch_bounds__(256, 4) void flash_attn(
    const bf16* __restrict__ Qb, const bf16* __restrict__ Kb,
    const bf16* __restrict__ Vb, bf16* __restrict__ Ob) {
  __shared__ __align__(16) char KsB[2][32 * 128];  // 8 KB
  __shared__ __align__(16) char VtB[2][64 * 64];   // 8 KB
  const int bh = blockIdx.y;
  const int q0 = blockIdx.x * 128;
  const int tid = threadIdx.x, lane = tid & 63, w = tid >> 6;
  const int l31 = lane & 31, hi = lane >> 5;
  const bf16* Qp = Qb + (size_t)bh * Nn * Dn;
  const bf16* Kp = Kb + (size_t)bh * Nn * Dn;
  const bf16* Vp = Vb + (size_t)bh * Nn * Dn;

  const int qrow = q0 + w * 32 + l31;
  bf16x8 qf[4];
#pragma unroll
  for (int dm = 0; dm < 4; ++dm)
    qf[dm] = *reinterpret_cast<const bf16x8*>(&Qp[(size_t)qrow * Dn + dm * 16 + hi * 8]);

  f32x16 Ot0 = {}, Ot1 = {};
  float m_r = -1e30f, l_r = 0.f;  // exp2 domain

  const int skk = tid >> 3, sd0 = (tid & 7) * 8;
  const int srcKe = (((sd0 * 2) ^ ((skk & 7) << 4)) >> 1);  // pre-swizzled src col

  auto stage_v = [&](char* Vn, const uint4& a) {
    const uint wa[4] = {a.x, a.y, a.z, a.w};
#pragma unroll
    for (int j = 0; j < 8; ++j) {
      const int d = sd0 + j;
      const int xs = (((d >> 1) ^ (d >> 3)) & 3) << 4;
      const unsigned short va = (j & 1) ? (unsigned short)(wa[j >> 1] >> 16)
                                        : (unsigned short)(wa[j >> 1] & 0xffff);
      *reinterpret_cast<unsigned short*>(Vn + d * 64 + ((skk * 2) ^ xs)) = va;
    }
  };

  GLOAD_LDS16(Kp + (size_t)skk * Dn + srcKe, KsB[0] + tid * 16);
  {
    uint4 cv = *reinterpret_cast<const uint4*>(&Vp[(size_t)skk * Dn + sd0]);
    stage_v(VtB[0], cv);
  }
  uint4 nv = *reinterpret_cast<const uint4*>(&Vp[(size_t)(32 + skk) * Dn + sd0]);
  __syncthreads();

  const int swzk_rd = (l31 & 7) << 4;
  const int xs0 = ((((l31) >> 1) ^ ((l31) >> 3)) & 3) << 4;
  const int xs1 = ((((32 + l31) >> 1) ^ ((32 + l31) >> 3)) & 3) << 4;
  int cur = 0;
  for (int k0 = 0; k0 < Nn; k0 += 32) {
    const char* Kc = KsB[cur];
    const char* Vc = VtB[cur];

    if (k0 + 32 < Nn) {
      GLOAD_LDS16(Kp + (size_t)(k0 + 32 + skk) * Dn + srcKe, KsB[cur ^ 1] + tid * 16);
      stage_v(VtB[cur ^ 1], nv);
      if (k0 + 64 < Nn)
        nv = *reinterpret_cast<const uint4*>(&Vp[(size_t)(k0 + 64 + skk) * Dn + sd0]);
    }

    // ---- S^T = K · Q^T : 4 MFMAs ----
    f32x16 S0 = {};
    __builtin_amdgcn_s_setprio(1);
#pragma unroll
    for (int dm = 0; dm < 4; ++dm) {
      bf16x8 kf = *reinterpret_cast<const bf16x8*>(
          Kc + l31 * 128 + ((dm * 32 + hi * 16) ^ swzk_rd));
      S0 = __builtin_amdgcn_mfma_f32_32x32x16_bf16(kf, qf[dm], S0, 0, 0, 0);
    }
    __builtin_amdgcn_s_setprio(0);

    // ---- online softmax (exp2 domain), lane-local; max via v_max3 chains ----
    float mx = fmaxf(fmaxf(S0[0], S0[1]), S0[2]);
    mx = fmaxf(fmaxf(mx, S0[3]), S0[4]);
    mx = fmaxf(fmaxf(mx, S0[5]), S0[6]);
    mx = fmaxf(fmaxf(mx, S0[7]), S0[8]);
    mx = fmaxf(fmaxf(mx, S0[9]), S0[10]);
    mx = fmaxf(fmaxf(mx, S0[11]), S0[12]);
    mx = fmaxf(fmaxf(mx, S0[13]), S0[14]);
    mx = fmaxf(mx, S0[15]);
    const float full = fmaxf(mx, __shfl_xor(mx, 32));
    if (__any(full > m_r + 8.f)) {  // defer-max (T13)
      const float mnew = fmaxf(m_r, full);
      const float al = exp2_raw(m_r - mnew);
#pragma unroll
      for (int i = 0; i < 16; ++i) { Ot0[i] *= al; Ot1[i] *= al; }
      l_r *= al;
      m_r = mnew;
    }
#pragma unroll
    for (int i = 0; i < 16; ++i) S0[i] = exp2_raw(S0[i] - m_r);
    float ps = 0.f;
    uint wv[8];
#pragma unroll
    for (int c = 0; c < 2; ++c) {
      ps += ((S0[8 * c + 0] + S0[8 * c + 1]) + (S0[8 * c + 2] + S0[8 * c + 3])) +
            ((S0[8 * c + 4] + S0[8 * c + 5]) + (S0[8 * c + 6] + S0[8 * c + 7]));
      uint w0, w1, w2, w3;
      asm("v_cvt_pk_bf16_f32 %0, %1, %2" : "=v"(w0) : "v"(S0[8 * c + 0]), "v"(S0[8 * c + 1]));
      asm("v_cvt_pk_bf16_f32 %0, %1, %2" : "=v"(w1) : "v"(S0[8 * c + 2]), "v"(S0[8 * c + 3]));
      asm("v_cvt_pk_bf16_f32 %0, %1, %2" : "=v"(w2) : "v"(S0[8 * c + 4]), "v"(S0[8 * c + 5]));
      asm("v_cvt_pk_bf16_f32 %0, %1, %2" : "=v"(w3) : "v"(S0[8 * c + 6]), "v"(S0[8 * c + 7]));
      asm("v_permlane32_swap_b32 %0, %1" : "+v"(w0), "+v"(w2));
      asm("v_permlane32_swap_b32 %0, %1" : "+v"(w1), "+v"(w3));
      wv[c * 4 + 0] = w0; wv[c * 4 + 1] = w1;
      wv[c * 4 + 2] = w2; wv[c * 4 + 3] = w3;
    }
    ps += __shfl_xor(ps, 32);
    l_r += ps;

    // ---- O^T += V^T · P^T : 4 MFMAs ----
    __builtin_amdgcn_s_setprio(1);
#pragma unroll
    for (int s = 0; s < 2; ++s) {
      const uint4 uu = {wv[s * 4 + 0], wv[s * 4 + 1], wv[s * 4 + 2], wv[s * 4 + 3]};
      const bf16x8 pa = __builtin_bit_cast(bf16x8, uu);
      bf16x8 vf0 = *reinterpret_cast<const bf16x8*>(
          Vc + l31 * 64 + ((s * 32 + hi * 16) ^ xs0));
      Ot0 = __builtin_amdgcn_mfma_f32_32x32x16_bf16(vf0, pa, Ot0, 0, 0, 0);
      bf16x8 vf1 = *reinterpret_cast<const bf16x8*>(
          Vc + (32 + l31) * 64 + ((s * 32 + hi * 16) ^ xs1));
      Ot1 = __builtin_amdgcn_mfma_f32_32x32x16_bf16(vf1, pa, Ot1, 0, 0, 0);
    }
    __builtin_amdgcn_s_setprio(0);

    __syncthreads();
    cur ^= 1;
  }

  // ---- epilogue ----
  const float inv = 1.f / l_r;
  const int b = bh >> 4, h = bh & 15;
#pragma unroll
  for (int dc = 0; dc < 2; ++dc)
#pragma unroll
    for (int a2 = 0; a2 < 4; ++a2) {
      const f32x16& O = dc ? Ot1 : Ot0;
      unsigned short u0 = __bfloat16_as_ushort(__float2bfloat16(O[a2 * 4 + 0] * inv));
      unsigned short u1 = __bfloat16_as_ushort(__float2bfloat16(O[a2 * 4 + 1] * inv));
      unsigned short u2 = __bfloat16_as_ushort(__float2bfloat16(O[a2 * 4 + 2] * inv));
      unsigned short u3 = __bfloat16_as_ushort(__float2bfloat16(O[a2 * 4 + 3] * inv));
      uint2 pk;
      pk.x = (uint)u0 | ((uint)u1 << 16);
      pk.y = (uint)u2 | ((uint)u3 << 16);
      const int col = h * 64 + dc * 32 + a2 * 8 + hi * 4;
      *reinterpret_cast<uint2*>(&Ob[((size_t)(b * Nn + qrow)) * Cn + col]) = pk;
    }
}

extern "C" void kernel_launch(void* const* d_in, const int* in_sizes, int n_in,
                              void* d_out, int out_size, void* d_ws, size_t ws_size,
                              hipStream_t stream) {
  const float* hs   = (const float*)d_in[0];
  const float* cosb = (const float*)d_in[1];
  const float* sinb = (const float*)d_in[2];
  const float* qkvw = (const float*)d_in[3];
  const float* outw = (const float*)d_in[4];
  const float* nqw  = (const float*)d_in[5];
  const float* nkw  = (const float*)d_in[6];
  float* out = (float*)d_out;

  char* ws = (char*)d_ws;
  size_t off = 0;
  bf16* hs_b   = (bf16*)(ws + off); off += (size_t)Bn * Nn * Cn * 2;
  bf16* qkvw_b = (bf16*)(ws + off); off += (size_t)3 * Cn * Cn * 2;
  bf16* outw_b = (bf16*)(ws + off); off += (size_t)Cn * Cn * 2;
  bf16* q_raw  = (bf16*)(ws + off); off += (size_t)Bn * Hn * Nn * Dn * 2;
  bf16* k_raw  = (bf16*)(ws + off); off += (size_t)Bn * Hn * Nn * Dn * 2;
  bf16* v_buf  = (bf16*)(ws + off); off += (size_t)Bn * Hn * Nn * Dn * 2;
  bf16* attn   = (bf16*)(ws + off); off += (size_t)Bn * Nn * Cn * 2;

  cvt_kernel<<<(Bn * Nn * Cn / 4 + 255) / 256, 256, 0, stream>>>(hs, hs_b, Bn * Nn * Cn / 4);
  cvt_kernel<<<(3 * Cn * Cn / 4 + 255) / 256, 256, 0, stream>>>(qkvw, qkvw_b, 3 * Cn * Cn / 4);
  cvt_kernel<<<(Cn * Cn / 4 + 255) / 256, 256, 0, stream>>>(outw, outw_b, Cn * Cn / 4);

  // QKV projection + fused RMSNorm/RoPE epilogue. grid 1D: 24 n-tiles x 64 m.
  gemm_bt<0><<<24 * 64, 256, 0, stream>>>(
      hs_b, qkvw_b, nullptr, q_raw, k_raw, v_buf, cosb, sinb, nqw, nkw,
      24, 64, 3 * Cn, Cn);

  flash_attn<<<dim3(Nn / 128, Bn * Hn), 256, 0, stream>>>(q_raw, k_raw, v_buf, attn);

  // out projection. grid 1D: 8 n-tiles x 64 m.
  gemm_bt<1><<<8 * 64, 256, 0, stream>>>(
      attn, outw_b, out, nullptr, nullptr, nullptr, nullptr, nullptr, nullptr, nullptr,
      8, 64, Cn, Cn);
}